// Round 4
// baseline (493.052 us; speedup 1.0000x reference)
//
#include <hip/hip_runtime.h>
#include <hip/hip_bf16.h>
#include <math.h>

#define H 512
#define B 64
#define L 4096

// ---------------------------------------------------------------------------
// Kernel 1: v[b,h] = sum_o hidden[b,o] * W[o,h];  c[b] = sum_o hidden[b,o]*bias[o]
// ---------------------------------------------------------------------------
__global__ __launch_bounds__(512) void proj_kernel(
    const float* __restrict__ hidden,   // [B,H]
    const float* __restrict__ W,        // [H,H]
    const float* __restrict__ bias,     // [H]
    float* __restrict__ v,              // [B,H]
    float* __restrict__ c)              // [B]
{
    const int b = blockIdx.x;
    const int h = threadIdx.x;

    __shared__ float hsh[H];
    hsh[h] = hidden[b * H + h];
    __syncthreads();

    float acc = 0.f;
#pragma unroll 8
    for (int o = 0; o < H; ++o) {
        acc = fmaf(hsh[o], W[o * H + h], acc);
    }
    v[b * H + h] = acc;

    float p = hsh[h] * bias[h];
#pragma unroll
    for (int off = 32; off; off >>= 1) p += __shfl_xor(p, off);

    __shared__ float red[8];
    if ((h & 63) == 0) red[h >> 6] = p;
    __syncthreads();
    if (h == 0) {
        float s = 0.f;
#pragma unroll
        for (int i = 0; i < 8; ++i) s += red[i];
        c[b] = s;
    }
}

// ---------------------------------------------------------------------------
// Kernel 2 (PROBE build): identical body to round 3, wrapped in a runtime
// `reps` loop so the dispatch outlasts the harness fills and its rocprof
// counters become visible in the top-5. asm keep-alives prevent rep DCE.
// ---------------------------------------------------------------------------
#define BG 4        // b's per wave
#define BPB 16      // b's per block
#define NL 16       // l's per wave

__global__ __launch_bounds__(256) void energies_kernel(
    const float* __restrict__ enc,      // [L,B,H]
    const float* __restrict__ v,        // [B,H]
    const float* __restrict__ c,        // [B]
    float* __restrict__ energies,       // [B,L]
    int reps)
{
    const int wave = threadIdx.x >> 6;
    const int lane = threadIdx.x & 63;

    const int nbg    = B / BPB;              // 4
    const int bgrp   = blockIdx.x % nbg;
    const int lchunk = blockIdx.x / nbg;
    const int l0     = lchunk * NL;
    const int b0     = bgrp * BPB + wave * BG;

    const float4* v4 = reinterpret_cast<const float4*>(v);
    float4 vf0[BG], vf1[BG];
    float  cb[BG];
#pragma unroll
    for (int r = 0; r < BG; ++r) {
        vf0[r] = v4[(size_t)(b0 + r) * 128 + lane];
        vf1[r] = v4[(size_t)(b0 + r) * 128 + 64 + lane];
        cb[r]  = c[b0 + r];
    }

    for (int rep = 0; rep < reps; ++rep) {
#pragma unroll 2
        for (int i = 0; i < NL; ++i) {
            const int l = l0 + i;
            const float4* chunk =
                reinterpret_cast<const float4*>(enc + ((size_t)l * B + b0) * H);

            float4 e[8];
#pragma unroll
            for (int k = 0; k < 8; ++k) e[k] = chunk[k * 64 + lane];

            float s[BG];
#pragma unroll
            for (int r = 0; r < BG; ++r) {
                const float4 ea = e[2 * r];
                const float4 eb = e[2 * r + 1];
                float t = ea.x * vf0[r].x + ea.y * vf0[r].y
                        + ea.z * vf0[r].z + ea.w * vf0[r].w;
                t = fmaf(eb.x, vf1[r].x, t);
                t = fmaf(eb.y, vf1[r].y, t);
                t = fmaf(eb.z, vf1[r].z, t);
                t = fmaf(eb.w, vf1[r].w, t);
                s[r] = t;
            }

#pragma unroll
            for (int off = 32; off; off >>= 1) {
#pragma unroll
                for (int r = 0; r < BG; ++r) s[r] += __shfl_xor(s[r], off);
            }

            // keep-alive: prevent rep-body DCE / store sinking (rule #17)
            asm volatile("" : : "v"(s[0]), "v"(s[1]), "v"(s[2]), "v"(s[3]));

            if (lane == 0) {
#pragma unroll
                for (int r = 0; r < BG; ++r)
                    energies[(size_t)(b0 + r) * L + l] = s[r] + cb[r];
            }
        }
    }
}

// ---------------------------------------------------------------------------
// Kernel 3: softmax over l per b.
// ---------------------------------------------------------------------------
__global__ __launch_bounds__(256) void softmax_kernel(
    const float* __restrict__ energies, // [B,L]
    float* __restrict__ out)            // [B,1,L]
{
    const int b = blockIdx.x;
    const int t = threadIdx.x;
    const float* e = energies + (size_t)b * L;
    float* o = out + (size_t)b * L;

    float vals[16];
    float m = -1e30f;
#pragma unroll
    for (int i = 0; i < 16; ++i) {
        vals[i] = e[t + i * 256];
        m = fmaxf(m, vals[i]);
    }
#pragma unroll
    for (int off = 32; off; off >>= 1) m = fmaxf(m, __shfl_xor(m, off));

    __shared__ float redm[4];
    if ((t & 63) == 0) redm[t >> 6] = m;
    __syncthreads();
    m = fmaxf(fmaxf(redm[0], redm[1]), fmaxf(redm[2], redm[3]));

    float s = 0.f;
#pragma unroll
    for (int i = 0; i < 16; ++i) {
        vals[i] = expf(vals[i] - m);
        s += vals[i];
    }
#pragma unroll
    for (int off = 32; off; off >>= 1) s += __shfl_xor(s, off);

    __shared__ float reds[4];
    if ((t & 63) == 0) reds[t >> 6] = s;
    __syncthreads();
    s = reds[0] + reds[1] + reds[2] + reds[3];

    const float inv = 1.0f / s;
#pragma unroll
    for (int i = 0; i < 16; ++i) o[t + i * 256] = vals[i] * inv;
}

// ---------------------------------------------------------------------------
extern "C" void kernel_launch(void* const* d_in, const int* in_sizes, int n_in,
                              void* d_out, int out_size, void* d_ws, size_t ws_size,
                              hipStream_t stream)
{
    const float* hidden = (const float*)d_in[0];   // [1,B,H]
    const float* enc    = (const float*)d_in[1];   // [L,B,H]
    const float* W      = (const float*)d_in[2];   // [H,H]
    const float* bias   = (const float*)d_in[3];   // [H]
    float* out = (float*)d_out;                    // [B,1,L]

    float* v        = (float*)d_ws;
    float* c        = v + (size_t)B * H;
    float* energies = c + B;

    proj_kernel<<<B, H, 0, stream>>>(hidden, W, bias, v, c);

    const int nblocks = (B / BPB) * (L / NL);      // 1024
    energies_kernel<<<nblocks, 256, 0, stream>>>(enc, v, c, energies, 5);

    softmax_kernel<<<B, 256, 0, stream>>>(energies, out);
}

// Round 5
// 106.057 us; speedup vs baseline: 4.6489x; 4.6489x over previous
//
#include <hip/hip_runtime.h>
#include <hip/hip_bf16.h>
#include <math.h>

#define H 512
#define B 64
#define L 4096

typedef float f32x4 __attribute__((ext_vector_type(4)));

// ---------------------------------------------------------------------------
// Kernel 1: v[b,h] = sum_o hidden[b,o] * W[o,h];  c[b] = sum_o hidden[b,o]*bias[o]
// 64 blocks (one per b), 512 threads (one per h). 4 independent acc chains.
// ---------------------------------------------------------------------------
__global__ __launch_bounds__(512) void proj_kernel(
    const float* __restrict__ hidden,   // [B,H]
    const float* __restrict__ W,        // [H,H]
    const float* __restrict__ bias,     // [H]
    float* __restrict__ v,              // [B,H]
    float* __restrict__ c)              // [B]
{
    const int b = blockIdx.x;
    const int h = threadIdx.x;

    __shared__ float hsh[H];
    hsh[h] = hidden[b * H + h];
    __syncthreads();

    float a0 = 0.f, a1 = 0.f, a2 = 0.f, a3 = 0.f;
#pragma unroll 2
    for (int o = 0; o < H; o += 4) {
        a0 = fmaf(hsh[o + 0], W[(o + 0) * H + h], a0);
        a1 = fmaf(hsh[o + 1], W[(o + 1) * H + h], a1);
        a2 = fmaf(hsh[o + 2], W[(o + 2) * H + h], a2);
        a3 = fmaf(hsh[o + 3], W[(o + 3) * H + h], a3);
    }
    v[b * H + h] = (a0 + a1) + (a2 + a3);

    float p = hsh[h] * bias[h];
#pragma unroll
    for (int off = 32; off; off >>= 1) p += __shfl_xor(p, off);

    __shared__ float red[8];
    if ((h & 63) == 0) red[h >> 6] = p;
    __syncthreads();
    if (h == 0) {
        float s = 0.f;
#pragma unroll
        for (int i = 0; i < 8; ++i) s += red[i];
        c[b] = s;
    }
}

// ---------------------------------------------------------------------------
// Kernel 2: energies[b,l] = enc[l,b,:] . v[b,:] + c[b]
// R3 structure (wave owns 4 consecutive b's, 8 KB contiguous per l), with
// enc loads marked NON-TEMPORAL (nt bit: no cache allocate on the streaming
// read path). v/c stay cached.
// ---------------------------------------------------------------------------
#define BG 4        // b's per wave
#define BPB 16      // b's per block
#define NL 16       // l's per wave

__global__ __launch_bounds__(256) void energies_kernel(
    const float* __restrict__ enc,      // [L,B,H]
    const float* __restrict__ v,        // [B,H]
    const float* __restrict__ c,        // [B]
    float* __restrict__ energies)       // [B,L]
{
    const int wave = threadIdx.x >> 6;
    const int lane = threadIdx.x & 63;

    const int nbg    = B / BPB;              // 4
    const int bgrp   = blockIdx.x % nbg;
    const int lchunk = blockIdx.x / nbg;
    const int l0     = lchunk * NL;
    const int b0     = bgrp * BPB + wave * BG;

    const f32x4* v4 = reinterpret_cast<const f32x4*>(v);
    f32x4 vf0[BG], vf1[BG];
    float cb[BG];
#pragma unroll
    for (int r = 0; r < BG; ++r) {
        vf0[r] = v4[(size_t)(b0 + r) * 128 + lane];
        vf1[r] = v4[(size_t)(b0 + r) * 128 + 64 + lane];
        cb[r]  = c[b0 + r];
    }

#pragma unroll 2
    for (int i = 0; i < NL; ++i) {
        const int l = l0 + i;
        const f32x4* chunk =
            reinterpret_cast<const f32x4*>(enc + ((size_t)l * B + b0) * H);

        f32x4 e[8];
#pragma unroll
        for (int k = 0; k < 8; ++k)
            e[k] = __builtin_nontemporal_load(chunk + k * 64 + lane);

        float s[BG];
#pragma unroll
        for (int r = 0; r < BG; ++r) {
            const f32x4 ea = e[2 * r];
            const f32x4 eb = e[2 * r + 1];
            float t = ea.x * vf0[r].x + ea.y * vf0[r].y
                    + ea.z * vf0[r].z + ea.w * vf0[r].w;
            t = fmaf(eb.x, vf1[r].x, t);
            t = fmaf(eb.y, vf1[r].y, t);
            t = fmaf(eb.z, vf1[r].z, t);
            t = fmaf(eb.w, vf1[r].w, t);
            s[r] = t;
        }

#pragma unroll
        for (int off = 32; off; off >>= 1) {
#pragma unroll
            for (int r = 0; r < BG; ++r) s[r] += __shfl_xor(s[r], off);
        }

        if (lane == 0) {
#pragma unroll
            for (int r = 0; r < BG; ++r)
                energies[(size_t)(b0 + r) * L + l] = s[r] + cb[r];
        }
    }
}

// ---------------------------------------------------------------------------
// Kernel 3: out[b,0,:] = softmax(energies[b,:])
// ---------------------------------------------------------------------------
__global__ __launch_bounds__(256) void softmax_kernel(
    const float* __restrict__ energies, // [B,L]
    float* __restrict__ out)            // [B,1,L]
{
    const int b = blockIdx.x;
    const int t = threadIdx.x;
    const float* e = energies + (size_t)b * L;
    float* o = out + (size_t)b * L;

    float vals[16];
    float m = -1e30f;
#pragma unroll
    for (int i = 0; i < 16; ++i) {
        vals[i] = e[t + i * 256];
        m = fmaxf(m, vals[i]);
    }
#pragma unroll
    for (int off = 32; off; off >>= 1) m = fmaxf(m, __shfl_xor(m, off));

    __shared__ float redm[4];
    if ((t & 63) == 0) redm[t >> 6] = m;
    __syncthreads();
    m = fmaxf(fmaxf(redm[0], redm[1]), fmaxf(redm[2], redm[3]));

    float s = 0.f;
#pragma unroll
    for (int i = 0; i < 16; ++i) {
        vals[i] = expf(vals[i] - m);
        s += vals[i];
    }
#pragma unroll
    for (int off = 32; off; off >>= 1) s += __shfl_xor(s, off);

    __shared__ float reds[4];
    if ((t & 63) == 0) reds[t >> 6] = s;
    __syncthreads();
    s = reds[0] + reds[1] + reds[2] + reds[3];

    const float inv = 1.0f / s;
#pragma unroll
    for (int i = 0; i < 16; ++i) o[t + i * 256] = vals[i] * inv;
}

// ---------------------------------------------------------------------------
extern "C" void kernel_launch(void* const* d_in, const int* in_sizes, int n_in,
                              void* d_out, int out_size, void* d_ws, size_t ws_size,
                              hipStream_t stream)
{
    const float* hidden = (const float*)d_in[0];   // [1,B,H]
    const float* enc    = (const float*)d_in[1];   // [L,B,H]
    const float* W      = (const float*)d_in[2];   // [H,H]
    const float* bias   = (const float*)d_in[3];   // [H]
    float* out = (float*)d_out;                    // [B,1,L]

    float* v        = (float*)d_ws;
    float* c        = v + (size_t)B * H;
    float* energies = c + B;

    proj_kernel<<<B, H, 0, stream>>>(hidden, W, bias, v, c);

    const int nblocks = (B / BPB) * (L / NL);      // 1024
    energies_kernel<<<nblocks, 256, 0, stream>>>(enc, v, c, energies);

    softmax_kernel<<<B, 256, 0, stream>>>(energies, out);
}

// Round 6
// 98.805 us; speedup vs baseline: 4.9901x; 1.0734x over previous
//
#include <hip/hip_runtime.h>
#include <hip/hip_bf16.h>
#include <math.h>

#define H 512
#define B 64
#define L 4096

typedef float f32x4 __attribute__((ext_vector_type(4)));

// ---------------------------------------------------------------------------
// Kernel 1: v[b,h] = sum_o hidden[b,o] * W[o,h];  c[b] = sum_o hidden[b,o]*bias[o]
// Latency-optimized: grid = B x 4 (h quarters) = 256 blocks (1 per CU),
// 1024 threads = 8-way o-split x 128 h. Per-thread chain: 64 loads / 4 FMA
// chains, fully unrolled. LDS reduce of the 8 o-partials (2-way alias, free).
// ---------------------------------------------------------------------------
__global__ __launch_bounds__(1024) void proj_kernel(
    const float* __restrict__ hidden,   // [B,H]
    const float* __restrict__ W,        // [H,H]
    const float* __restrict__ bias,     // [H]
    float* __restrict__ v,              // [B,H]
    float* __restrict__ c)              // [B]
{
    const int b  = blockIdx.x >> 2;
    const int hq = blockIdx.x & 3;
    const int os = threadIdx.x >> 7;    // 0..7 : o-chunk
    const int hh = threadIdx.x & 127;   // 0..127
    const int h  = hq * 128 + hh;

    __shared__ float hsh[H];
    __shared__ float psum[8][128];

    if (threadIdx.x < H) hsh[threadIdx.x] = hidden[b * H + threadIdx.x];
    __syncthreads();

    const int o0 = os * 64;
    float a0 = 0.f, a1 = 0.f, a2 = 0.f, a3 = 0.f;
#pragma unroll
    for (int k = 0; k < 64; k += 4) {
        a0 = fmaf(hsh[o0 + k + 0], W[(size_t)(o0 + k + 0) * H + h], a0);
        a1 = fmaf(hsh[o0 + k + 1], W[(size_t)(o0 + k + 1) * H + h], a1);
        a2 = fmaf(hsh[o0 + k + 2], W[(size_t)(o0 + k + 2) * H + h], a2);
        a3 = fmaf(hsh[o0 + k + 3], W[(size_t)(o0 + k + 3) * H + h], a3);
    }
    psum[os][hh] = (a0 + a1) + (a2 + a3);
    __syncthreads();

    if (os == 0) {
        float s = 0.f;
#pragma unroll
        for (int k = 0; k < 8; ++k) s += psum[k][hh];
        v[(size_t)b * H + h] = s;
    }

    // c[b] = dot(hidden[b,:], bias) — computed by the hq==0 block only
    if (hq == 0) {
        __shared__ float red[8];
        if (threadIdx.x < H) {
            float p = hsh[threadIdx.x] * bias[threadIdx.x];
#pragma unroll
            for (int off = 32; off; off >>= 1) p += __shfl_xor(p, off);
            if ((threadIdx.x & 63) == 0) red[threadIdx.x >> 6] = p;
        }
        __syncthreads();
        if (threadIdx.x == 0) {
            float s = 0.f;
#pragma unroll
            for (int i = 0; i < 8; ++i) s += red[i];
            c[b] = s;
        }
    }
}

// ---------------------------------------------------------------------------
// Kernel 2 (UNCHANGED from round 5 — near read-BW ceiling):
// energies[b,l] = enc[l,b,:] . v[b,:] + c[b]; enc via non-temporal loads.
// ---------------------------------------------------------------------------
#define BG 4        // b's per wave
#define BPB 16      // b's per block
#define NL 16       // l's per wave

__global__ __launch_bounds__(256) void energies_kernel(
    const float* __restrict__ enc,      // [L,B,H]
    const float* __restrict__ v,        // [B,H]
    const float* __restrict__ c,        // [B]
    float* __restrict__ energies)       // [B,L]
{
    const int wave = threadIdx.x >> 6;
    const int lane = threadIdx.x & 63;

    const int nbg    = B / BPB;              // 4
    const int bgrp   = blockIdx.x % nbg;
    const int lchunk = blockIdx.x / nbg;
    const int l0     = lchunk * NL;
    const int b0     = bgrp * BPB + wave * BG;

    const f32x4* v4 = reinterpret_cast<const f32x4*>(v);
    f32x4 vf0[BG], vf1[BG];
    float cb[BG];
#pragma unroll
    for (int r = 0; r < BG; ++r) {
        vf0[r] = v4[(size_t)(b0 + r) * 128 + lane];
        vf1[r] = v4[(size_t)(b0 + r) * 128 + 64 + lane];
        cb[r]  = c[b0 + r];
    }

#pragma unroll 2
    for (int i = 0; i < NL; ++i) {
        const int l = l0 + i;
        const f32x4* chunk =
            reinterpret_cast<const f32x4*>(enc + ((size_t)l * B + b0) * H);

        f32x4 e[8];
#pragma unroll
        for (int k = 0; k < 8; ++k)
            e[k] = __builtin_nontemporal_load(chunk + k * 64 + lane);

        float s[BG];
#pragma unroll
        for (int r = 0; r < BG; ++r) {
            const f32x4 ea = e[2 * r];
            const f32x4 eb = e[2 * r + 1];
            float t = ea.x * vf0[r].x + ea.y * vf0[r].y
                    + ea.z * vf0[r].z + ea.w * vf0[r].w;
            t = fmaf(eb.x, vf1[r].x, t);
            t = fmaf(eb.y, vf1[r].y, t);
            t = fmaf(eb.z, vf1[r].z, t);
            t = fmaf(eb.w, vf1[r].w, t);
            s[r] = t;
        }

#pragma unroll
        for (int off = 32; off; off >>= 1) {
#pragma unroll
            for (int r = 0; r < BG; ++r) s[r] += __shfl_xor(s[r], off);
        }

        if (lane == 0) {
#pragma unroll
            for (int r = 0; r < BG; ++r)
                energies[(size_t)(b0 + r) * L + l] = s[r] + cb[r];
        }
    }
}

// ---------------------------------------------------------------------------
// Kernel 3: out[b,0,:] = softmax(energies[b,:])
// ---------------------------------------------------------------------------
__global__ __launch_bounds__(256) void softmax_kernel(
    const float* __restrict__ energies, // [B,L]
    float* __restrict__ out)            // [B,1,L]
{
    const int b = blockIdx.x;
    const int t = threadIdx.x;
    const float* e = energies + (size_t)b * L;
    float* o = out + (size_t)b * L;

    float vals[16];
    float m = -1e30f;
#pragma unroll
    for (int i = 0; i < 16; ++i) {
        vals[i] = e[t + i * 256];
        m = fmaxf(m, vals[i]);
    }
#pragma unroll
    for (int off = 32; off; off >>= 1) m = fmaxf(m, __shfl_xor(m, off));

    __shared__ float redm[4];
    if ((t & 63) == 0) redm[t >> 6] = m;
    __syncthreads();
    m = fmaxf(fmaxf(redm[0], redm[1]), fmaxf(redm[2], redm[3]));

    float s = 0.f;
#pragma unroll
    for (int i = 0; i < 16; ++i) {
        vals[i] = expf(vals[i] - m);
        s += vals[i];
    }
#pragma unroll
    for (int off = 32; off; off >>= 1) s += __shfl_xor(s, off);

    __shared__ float reds[4];
    if ((t & 63) == 0) reds[t >> 6] = s;
    __syncthreads();
    s = reds[0] + reds[1] + reds[2] + reds[3];

    const float inv = 1.0f / s;
#pragma unroll
    for (int i = 0; i < 16; ++i) o[t + i * 256] = vals[i] * inv;
}

// ---------------------------------------------------------------------------
extern "C" void kernel_launch(void* const* d_in, const int* in_sizes, int n_in,
                              void* d_out, int out_size, void* d_ws, size_t ws_size,
                              hipStream_t stream)
{
    const float* hidden = (const float*)d_in[0];   // [1,B,H]
    const float* enc    = (const float*)d_in[1];   // [L,B,H]
    const float* W      = (const float*)d_in[2];   // [H,H]
    const float* bias   = (const float*)d_in[3];   // [H]
    float* out = (float*)d_out;                    // [B,1,L]

    float* v        = (float*)d_ws;
    float* c        = v + (size_t)B * H;
    float* energies = c + B;

    proj_kernel<<<B * 4, 1024, 0, stream>>>(hidden, W, bias, v, c);

    const int nblocks = (B / BPB) * (L / NL);      // 1024
    energies_kernel<<<nblocks, 256, 0, stream>>>(enc, v, c, energies);

    softmax_kernel<<<B, 256, 0, stream>>>(energies, out);
}

// Round 7
// 96.536 us; speedup vs baseline: 5.1075x; 1.0235x over previous
//
#include <hip/hip_runtime.h>
#include <hip/hip_bf16.h>
#include <math.h>

#define H 512
#define B 64
#define L 4096

typedef float f32x4 __attribute__((ext_vector_type(4)));

// ---------------------------------------------------------------------------
// Kernel 1: v[b,h] = sum_o hidden[b,o] * W[o,h];  c[b] = sum_o hidden[b,o]*bias[o]
// grid = B x 4 (h quarters) = 256 blocks, 1024 threads = 8-way o-split x 128 h.
// ---------------------------------------------------------------------------
__global__ __launch_bounds__(1024) void proj_kernel(
    const float* __restrict__ hidden,   // [B,H]
    const float* __restrict__ W,        // [H,H]
    const float* __restrict__ bias,     // [H]
    float* __restrict__ v,              // [B,H]
    float* __restrict__ c)              // [B]
{
    const int b  = blockIdx.x >> 2;
    const int hq = blockIdx.x & 3;
    const int os = threadIdx.x >> 7;    // 0..7 : o-chunk
    const int hh = threadIdx.x & 127;   // 0..127
    const int h  = hq * 128 + hh;

    __shared__ float hsh[H];
    __shared__ float psum[8][128];

    if (threadIdx.x < H) hsh[threadIdx.x] = hidden[b * H + threadIdx.x];
    __syncthreads();

    const int o0 = os * 64;
    float a0 = 0.f, a1 = 0.f, a2 = 0.f, a3 = 0.f;
#pragma unroll
    for (int k = 0; k < 64; k += 4) {
        a0 = fmaf(hsh[o0 + k + 0], W[(size_t)(o0 + k + 0) * H + h], a0);
        a1 = fmaf(hsh[o0 + k + 1], W[(size_t)(o0 + k + 1) * H + h], a1);
        a2 = fmaf(hsh[o0 + k + 2], W[(size_t)(o0 + k + 2) * H + h], a2);
        a3 = fmaf(hsh[o0 + k + 3], W[(size_t)(o0 + k + 3) * H + h], a3);
    }
    psum[os][hh] = (a0 + a1) + (a2 + a3);
    __syncthreads();

    if (os == 0) {
        float s = 0.f;
#pragma unroll
        for (int k = 0; k < 8; ++k) s += psum[k][hh];
        v[(size_t)b * H + h] = s;
    }

    if (hq == 0) {
        __shared__ float red[8];
        if (threadIdx.x < H) {
            float p = hsh[threadIdx.x] * bias[threadIdx.x];
#pragma unroll
            for (int off = 32; off; off >>= 1) p += __shfl_xor(p, off);
            if ((threadIdx.x & 63) == 0) red[threadIdx.x >> 6] = p;
        }
        __syncthreads();
        if (threadIdx.x == 0) {
            float s = 0.f;
#pragma unroll
            for (int i = 0; i < 8; ++i) s += red[i];
            c[b] = s;
        }
    }
}

// ---------------------------------------------------------------------------
// Kernel 2: energies[b,l] = enc[l,b,:] . v[b,:] + c[b]
// NT loads on enc (round-5 win). Round-7 change: NL 16 -> 8, grid 1024 -> 2048
// blocks = 8 blocks/CU = 32 waves/CU, doubling in-flight NT reads per CU.
// ---------------------------------------------------------------------------
#define BG 4        // b's per wave
#define BPB 16      // b's per block
#define NL 8        // l's per wave  (was 16)

__global__ __launch_bounds__(256) void energies_kernel(
    const float* __restrict__ enc,      // [L,B,H]
    const float* __restrict__ v,        // [B,H]
    const float* __restrict__ c,        // [B]
    float* __restrict__ energies)       // [B,L]
{
    const int wave = threadIdx.x >> 6;
    const int lane = threadIdx.x & 63;

    const int nbg    = B / BPB;              // 4
    const int bgrp   = blockIdx.x % nbg;
    const int lchunk = blockIdx.x / nbg;
    const int l0     = lchunk * NL;
    const int b0     = bgrp * BPB + wave * BG;

    const f32x4* v4 = reinterpret_cast<const f32x4*>(v);
    f32x4 vf0[BG], vf1[BG];
    float cb[BG];
#pragma unroll
    for (int r = 0; r < BG; ++r) {
        vf0[r] = v4[(size_t)(b0 + r) * 128 + lane];
        vf1[r] = v4[(size_t)(b0 + r) * 128 + 64 + lane];
        cb[r]  = c[b0 + r];
    }

#pragma unroll 2
    for (int i = 0; i < NL; ++i) {
        const int l = l0 + i;
        const f32x4* chunk =
            reinterpret_cast<const f32x4*>(enc + ((size_t)l * B + b0) * H);

        f32x4 e[8];
#pragma unroll
        for (int k = 0; k < 8; ++k)
            e[k] = __builtin_nontemporal_load(chunk + k * 64 + lane);

        float s[BG];
#pragma unroll
        for (int r = 0; r < BG; ++r) {
            const f32x4 ea = e[2 * r];
            const f32x4 eb = e[2 * r + 1];
            float t = ea.x * vf0[r].x + ea.y * vf0[r].y
                    + ea.z * vf0[r].z + ea.w * vf0[r].w;
            t = fmaf(eb.x, vf1[r].x, t);
            t = fmaf(eb.y, vf1[r].y, t);
            t = fmaf(eb.z, vf1[r].z, t);
            t = fmaf(eb.w, vf1[r].w, t);
            s[r] = t;
        }

#pragma unroll
        for (int off = 32; off; off >>= 1) {
#pragma unroll
            for (int r = 0; r < BG; ++r) s[r] += __shfl_xor(s[r], off);
        }

        if (lane == 0) {
#pragma unroll
            for (int r = 0; r < BG; ++r)
                energies[(size_t)(b0 + r) * L + l] = s[r] + cb[r];
        }
    }
}

// ---------------------------------------------------------------------------
// Kernel 3: out[b,0,:] = softmax(energies[b,:])
// ---------------------------------------------------------------------------
__global__ __launch_bounds__(256) void softmax_kernel(
    const float* __restrict__ energies, // [B,L]
    float* __restrict__ out)            // [B,1,L]
{
    const int b = blockIdx.x;
    const int t = threadIdx.x;
    const float* e = energies + (size_t)b * L;
    float* o = out + (size_t)b * L;

    float vals[16];
    float m = -1e30f;
#pragma unroll
    for (int i = 0; i < 16; ++i) {
        vals[i] = e[t + i * 256];
        m = fmaxf(m, vals[i]);
    }
#pragma unroll
    for (int off = 32; off; off >>= 1) m = fmaxf(m, __shfl_xor(m, off));

    __shared__ float redm[4];
    if ((t & 63) == 0) redm[t >> 6] = m;
    __syncthreads();
    m = fmaxf(fmaxf(redm[0], redm[1]), fmaxf(redm[2], redm[3]));

    float s = 0.f;
#pragma unroll
    for (int i = 0; i < 16; ++i) {
        vals[i] = expf(vals[i] - m);
        s += vals[i];
    }
#pragma unroll
    for (int off = 32; off; off >>= 1) s += __shfl_xor(s, off);

    __shared__ float reds[4];
    if ((t & 63) == 0) reds[t >> 6] = s;
    __syncthreads();
    s = reds[0] + reds[1] + reds[2] + reds[3];

    const float inv = 1.0f / s;
#pragma unroll
    for (int i = 0; i < 16; ++i) o[t + i * 256] = vals[i] * inv;
}

// ---------------------------------------------------------------------------
extern "C" void kernel_launch(void* const* d_in, const int* in_sizes, int n_in,
                              void* d_out, int out_size, void* d_ws, size_t ws_size,
                              hipStream_t stream)
{
    const float* hidden = (const float*)d_in[0];   // [1,B,H]
    const float* enc    = (const float*)d_in[1];   // [L,B,H]
    const float* W      = (const float*)d_in[2];   // [H,H]
    const float* bias   = (const float*)d_in[3];   // [H]
    float* out = (float*)d_out;                    // [B,1,L]

    float* v        = (float*)d_ws;
    float* c        = v + (size_t)B * H;
    float* energies = c + B;

    proj_kernel<<<B * 4, 1024, 0, stream>>>(hidden, W, bias, v, c);

    const int nblocks = (B / BPB) * (L / NL);      // 4 * 512 = 2048
    energies_kernel<<<nblocks, 256, 0, stream>>>(enc, v, c, energies);

    softmax_kernel<<<B, 256, 0, stream>>>(energies, out);
}